// Round 2
// baseline (195.525 us; speedup 1.0000x reference)
//
#include <hip/hip_runtime.h>

// Problem constants (fixed shape: B=1, H=2048, W=3072)
constexpr int Wd = 3072;
constexpr int WC = 14;   // window size

// Native clang vector type: __builtin_nontemporal_store requires a real
// vector type, not HIP's HIP_vector_type<float,4> class.
typedef float fvec4 __attribute__((ext_vector_type(4)));

// One block = 1/3 of one row. 256 threads, each thread computes 4 consecutive
// outputs (one float4) for all 6 output planes. No LDS, no barrier: the
// x/z halos are read directly from global as aligned float4 (lane stride
// 16 B -> every load instruction is a fully-coalesced 1 KB transaction;
// the overlap between neighboring lanes is served by L1). Outputs are
// written with nontemporal float4 stores (never re-read; keeps L2 clean
// for the x/z reads).
__global__ __launch_bounds__(256, 2)
void color_restore_kernel(const float* __restrict__ xg,
                          const float* __restrict__ zg,
                          float* __restrict__ out, int Hn)
{
    const int h   = blockIdx.y;       // row
    const int seg = blockIdx.x;       // 0..2 (thirds of a row)
    const int t   = threadIdx.x;
    const int w0  = seg * 1024 + 4 * t;

    const float* __restrict__ xrow = xg + (size_t)h * Wd;
    const float* __restrict__ zrow = zg + (size_t)h * Wd;

    // Register halos:
    //   xb[i] = x[w0 - 12 + i], i = 0..27   (covers x[w0-10 .. w0+13])
    //   zb[i] = z[w0 - 16 + i], i = 0..19   (covers z[w0-13 .. w0+3])
    float xb[28];
    float zb[20];

    if (w0 >= 16 && w0 <= Wd - 16) {
        // Fast path: all reads in-bounds, 16B-aligned (w0 % 4 == 0).
        const fvec4* xp4 = (const fvec4*)(xrow + (w0 - 12));
        const fvec4* zp4 = (const fvec4*)(zrow + (w0 - 16));
        fvec4 xq[7], zq[5];
#pragma unroll
        for (int i = 0; i < 7; ++i) xq[i] = xp4[i];
#pragma unroll
        for (int i = 0; i < 5; ++i) zq[i] = zp4[i];
#pragma unroll
        for (int i = 0; i < 7; ++i) {
            xb[4 * i + 0] = xq[i].x; xb[4 * i + 1] = xq[i].y;
            xb[4 * i + 2] = xq[i].z; xb[4 * i + 3] = xq[i].w;
        }
#pragma unroll
        for (int i = 0; i < 5; ++i) {
            zb[4 * i + 0] = zq[i].x; zb[4 * i + 1] = zq[i].y;
            zb[4 * i + 2] = zq[i].z; zb[4 * i + 3] = zq[i].w;
        }
    } else {
        // Edge path (7 threads per row of 768): guarded scalar loads,
        // zero outside [0, Wd) == the reference's zero padding.
#pragma unroll
        for (int i = 0; i < 28; ++i) {
            const int k = w0 - 12 + i;
            xb[i] = (k >= 0 && k < Wd) ? xrow[k] : 0.f;
        }
#pragma unroll
        for (int i = 0; i < 20; ++i) {
            const int k = w0 - 16 + i;
            zb[i] = (k >= 0 && k < Wd) ? zrow[k] : 0.f;
        }
    }

    // ---- initial 14-tap window at w = w0 ----
    // Relative indexing: z[w0+d] == zb[16+d] (d in [-13,3])
    //                    x[w0+d] == xb[12+d] (d in [-10,13])
    float den = 0.f, n0 = 0.f, n1 = 0.f, n2 = 0.f;
#pragma unroll
    for (int s = 0; s < WC; ++s) {       // j = w0 - 13 + s
        const float zj = zb[3 + s];
        den += zj;
        n0 = fmaf(xb[s + 2], zj, n0);    // x[j+3]
        n1 = fmaf(xb[s + 6], zj, n1);    // x[j+7]
        n2 = fmaf(xb[s + 9], zj, n2);    // x[j+10]
    }

    float y0[4], y1[4], y2[4];
#pragma unroll
    for (int q = 0; q < 4; ++q) {        // w = w0 + q
        if (q > 0) {
            const float zin = zb[16 + q];                   // z[w]
            const float zot = zb[2 + q];                    // z[w-14]
            den += zin - zot;
            n0 += xb[15 + q] * zin - xb[1 + q] * zot;       // x[w+3],  x[w-11]
            n1 += xb[19 + q] * zin - xb[5 + q] * zot;       // x[w+7],  x[w-7]
            n2 += xb[22 + q] * zin - xb[8 + q] * zot;       // x[w+10], x[w-4]
        }
        const float rinv = __builtin_amdgcn_rcpf(den);
        y0[q] = n0 * rinv;
        y1[q] = n1 * rinv;
        y2[q] = n2 * rinv;
    }

    // ---- coalesced nontemporal float4 stores ----
    const int plane = Hn * Wd;           // 6291456, fits int
    const int off   = h * Wd + w0;
    float* yout = out;
    float* rout = out + 3 * (size_t)plane;

    fvec4 v;
    v.x = y0[0]; v.y = y0[1]; v.z = y0[2]; v.w = y0[3];
    __builtin_nontemporal_store(v, (fvec4*)(yout + off));
    v.x = y1[0]; v.y = y1[1]; v.z = y1[2]; v.w = y1[3];
    __builtin_nontemporal_store(v, (fvec4*)(yout + plane + off));
    v.x = y2[0]; v.y = y2[1]; v.z = y2[2]; v.w = y2[3];
    __builtin_nontemporal_store(v, (fvec4*)(yout + 2 * plane + off));
    // r0 = z[w-3] -> zb[13..16], r1 = z[w-7] -> zb[9..12], r2 = z[w-10] -> zb[6..9]
    v.x = zb[13]; v.y = zb[14]; v.z = zb[15]; v.w = zb[16];
    __builtin_nontemporal_store(v, (fvec4*)(rout + off));
    v.x = zb[9]; v.y = zb[10]; v.z = zb[11]; v.w = zb[12];
    __builtin_nontemporal_store(v, (fvec4*)(rout + plane + off));
    v.x = zb[6]; v.y = zb[7]; v.z = zb[8]; v.w = zb[9];
    __builtin_nontemporal_store(v, (fvec4*)(rout + 2 * plane + off));
}

extern "C" void kernel_launch(void* const* d_in, const int* in_sizes, int n_in,
                              void* d_out, int out_size, void* d_ws, size_t ws_size,
                              hipStream_t stream)
{
    const float* x = (const float*)d_in[0];
    const float* z = (const float*)d_in[1];
    float* out = (float*)d_out;
    const int Hn = in_sizes[0] / Wd;   // 2048
    color_restore_kernel<<<dim3(3, Hn), dim3(256), 0, stream>>>(x, z, out, Hn);
}

// Round 4
// 191.509 us; speedup vs baseline: 1.0210x; 1.0210x over previous
//
#include <hip/hip_runtime.h>

// Problem constants (fixed shape: B=1, H=2048, W=3072)
constexpr int Wd = 3072;
constexpr int WC = 14;   // window size

typedef float fvec4 __attribute__((ext_vector_type(4)));

// Block = one third of one row (1024 outputs), 256 threads, 4 outputs/thread,
// single pass. Inputs staged once into a small LDS tile (8.4 KB) with halos,
// so every input float is read from global exactly once (coalesced float4).
// All 6 output-plane stores are coalesced nontemporal float4.
//
// LDS layout (float4 granularity; all halo blocks are FULLY in- or out-of-
// bounds because pads are multiples of 4):
//   xs4[i] <-> global x float4 block (seg*256 - 3 + i),  i in [0,263)
//              i.e. xs float j <-> x[seg*1024 - 12 + j]
//   zs4[i] <-> global z float4 block (seg*256 - 4 + i),  i in [0,260)
//              i.e. zs float j <-> z[seg*1024 - 16 + j]
constexpr int XNQ = 263;   // x float4 blocks staged (halo: -12 .. +16)
constexpr int ZNQ = 260;   // z float4 blocks staged (halo: -16 .. +0)

__global__ __launch_bounds__(256, 4)
void color_restore_kernel(const float* __restrict__ xg,
                          const float* __restrict__ zg,
                          float* __restrict__ out, int Hn)
{
    __shared__ __align__(16) float xs[XNQ * 4];   // 1052 floats
    __shared__ __align__(16) float zs[ZNQ * 4];   // 1040 floats

    const int h   = blockIdx.y;       // row
    const int seg = blockIdx.x;       // 0..2 (thirds of a row)
    const int t   = threadIdx.x;

    const fvec4* xrow4 = (const fvec4*)(xg + (size_t)h * Wd);
    const fvec4* zrow4 = (const fvec4*)(zg + (size_t)h * Wd);
    fvec4* xs4 = (fvec4*)xs;
    fvec4* zs4 = (fvec4*)zs;

    const int gx0 = seg * 256 - 3;    // global float4 idx of xs4[0]
    const int gz0 = seg * 256 - 4;    // global float4 idx of zs4[0]
    const fvec4 zero4 = {0.f, 0.f, 0.f, 0.f};

    // ---- stage (each global float4 touched exactly once; OOB -> zero pad) ----
    {
        int g = gx0 + t;
        xs4[t] = (g >= 0 && g < Wd / 4) ? xrow4[g] : zero4;
        if (t < XNQ - 256) {                       // 7 threads
            g = gx0 + 256 + t;
            xs4[256 + t] = (g >= 0 && g < Wd / 4) ? xrow4[g] : zero4;
        }
        g = gz0 + t;
        zs4[t] = (g >= 0 && g < Wd / 4) ? zrow4[g] : zero4;
        if (t < ZNQ - 256) {                       // 4 threads
            zs4[256 + t] = ((gz0 + 256 + t) >= 0 && (gz0 + 256 + t) < Wd / 4)
                               ? zrow4[gz0 + 256 + t] : zero4;
        }
    }
    __syncthreads();

    // ---- pull halo spans from LDS as aligned float4 ----
    // w0g = seg*1024 + 4t (global output index of this thread's first output)
    // zbuf[i] = zs[4t + i] = z[w0g - 16 + i]  ->  z[w0g+d] == zbuf[16+d]
    // xbuf[i] = xs[4t + i] = x[w0g - 12 + i]  ->  x[w0g+d] == xbuf[12+d]
    float zbuf[20], xbuf[28];
    {
        fvec4* zb = (fvec4*)zbuf;
        fvec4* xb = (fvec4*)xbuf;
#pragma unroll
        for (int i = 0; i < 5; ++i) zb[i] = zs4[t + i];
#pragma unroll
        for (int i = 0; i < 7; ++i) xb[i] = xs4[t + i];
    }

    // ---- initial 14-tap window at w = w0g ----
    float den = 0.f, n0 = 0.f, n1 = 0.f, n2 = 0.f;
#pragma unroll
    for (int s = 0; s < WC; ++s) {       // j = w0g - 13 + s
        const float zj = zbuf[3 + s];
        den += zj;
        n0 = fmaf(xbuf[s + 2], zj, n0);  // x[j+3]
        n1 = fmaf(xbuf[s + 6], zj, n1);  // x[j+7]
        n2 = fmaf(xbuf[s + 9], zj, n2);  // x[j+10]
    }

    float y0[4], y1[4], y2[4];
#pragma unroll
    for (int q = 0; q < 4; ++q) {        // w = w0g + q
        if (q > 0) {
            const float zin = zbuf[16 + q];                 // z[w]
            const float zot = zbuf[2 + q];                  // z[w-14]
            den += zin - zot;
            n0 += xbuf[15 + q] * zin - xbuf[1 + q] * zot;   // x[w+3],  x[w-11]
            n1 += xbuf[19 + q] * zin - xbuf[5 + q] * zot;   // x[w+7],  x[w-7]
            n2 += xbuf[22 + q] * zin - xbuf[8 + q] * zot;   // x[w+10], x[w-4]
        }
        const float rinv = __builtin_amdgcn_rcpf(den);
        y0[q] = n0 * rinv;
        y1[q] = n1 * rinv;
        y2[q] = n2 * rinv;
    }

    // ---- coalesced nontemporal float4 stores ----
    const int plane = Hn * Wd;           // 6291456, fits int
    const int off   = h * Wd + seg * 1024 + 4 * t;
    float* yout = out;
    float* rout = out + 3 * (size_t)plane;

    fvec4 v;
    v.x = y0[0]; v.y = y0[1]; v.z = y0[2]; v.w = y0[3];
    __builtin_nontemporal_store(v, (fvec4*)(yout + off));
    v.x = y1[0]; v.y = y1[1]; v.z = y1[2]; v.w = y1[3];
    __builtin_nontemporal_store(v, (fvec4*)(yout + plane + off));
    v.x = y2[0]; v.y = y2[1]; v.z = y2[2]; v.w = y2[3];
    __builtin_nontemporal_store(v, (fvec4*)(yout + 2 * plane + off));
    // r0 = z[w-3] -> zbuf[13..16], r1 = z[w-7] -> zbuf[9..12], r2 = z[w-10] -> zbuf[6..9]
    v.x = zbuf[13]; v.y = zbuf[14]; v.z = zbuf[15]; v.w = zbuf[16];
    __builtin_nontemporal_store(v, (fvec4*)(rout + off));
    v.x = zbuf[9]; v.y = zbuf[10]; v.z = zbuf[11]; v.w = zbuf[12];
    __builtin_nontemporal_store(v, (fvec4*)(rout + plane + off));
    v.x = zbuf[6]; v.y = zbuf[7]; v.z = zbuf[8]; v.w = zbuf[9];
    __builtin_nontemporal_store(v, (fvec4*)(rout + 2 * plane + off));
}

extern "C" void kernel_launch(void* const* d_in, const int* in_sizes, int n_in,
                              void* d_out, int out_size, void* d_ws, size_t ws_size,
                              hipStream_t stream)
{
    const float* x = (const float*)d_in[0];
    const float* z = (const float*)d_in[1];
    float* out = (float*)d_out;
    const int Hn = in_sizes[0] / Wd;   // 2048
    color_restore_kernel<<<dim3(3, Hn), dim3(256), 0, stream>>>(x, z, out, Hn);
}